// Round 1
// baseline (154.457 us; speedup 1.0000x reference)
//
#include <hip/hip_runtime.h>
#include <hip/hip_bf16.h>

// out[b,k] = sum_i x[b,i] * M[i,k],  M[i,k] = sign(i, i^k) * w[i^k]
// sign(a,b) = (-1)^{sum_{s>=1} popcount((a>>s) & b)}  (P=6,Q=0,R=0 -> metric all +1)

#define DIM 64
#define TILE_ROWS 256

__global__ void build_M_kernel(const float* __restrict__ w, float* __restrict__ M) {
    int t = threadIdx.x + blockIdx.x * blockDim.x;   // 0..4095
    if (t >= DIM * DIM) return;
    int i = t >> 6;
    int k = t & 63;
    int j = i ^ k;
    int aa = i >> 1;
    int cnt = 0;
    while (aa) { cnt += __popc(aa & j); aa >>= 1; }
    float s = (cnt & 1) ? -1.0f : 1.0f;
    M[t] = s * w[j];
}

__global__ __launch_bounds__(TILE_ROWS, 2)
void gp_main_kernel(const float* __restrict__ x,
                    const float* __restrict__ M,
                    float* __restrict__ out,
                    int nrows) {
    // 64 KB LDS: 256 rows x 16 float4, XOR-swizzled within each row
    __shared__ float4 lds[TILE_ROWS * 16];

    const int tid = threadIdx.x;
    const long long base = (long long)blockIdx.x * TILE_ROWS;

    // ---- phase 1: coalesced cooperative load of the 256-row tile ----
    const float4* __restrict__ xin = (const float4*)(x + base * DIM);
    #pragma unroll
    for (int it = 0; it < 16; ++it) {
        int idx = it * TILE_ROWS + tid;       // float4 index in tile
        int r = idx >> 4;
        int c = idx & 15;
        lds[(r << 4) | (c ^ (r & 15))] = xin[idx];
    }
    __syncthreads();

    // ---- phase 2: each thread computes its own row ----
    float acc[DIM];
    #pragma unroll
    for (int k = 0; k < DIM; ++k) acc[k] = 0.0f;

    #pragma unroll 1
    for (int ic = 0; ic < 4; ++ic) {          // 16 i's per chunk
        float xi[16];
        #pragma unroll
        for (int g = 0; g < 4; ++g) {
            float4 v = lds[(tid << 4) | ((ic * 4 + g) ^ (tid & 15))];
            xi[g * 4 + 0] = v.x;
            xi[g * 4 + 1] = v.y;
            xi[g * 4 + 2] = v.z;
            xi[g * 4 + 3] = v.w;
        }
        #pragma unroll
        for (int ii = 0; ii < 16; ++ii) {
            const int i = ic * 16 + ii;
            const float* __restrict__ Mr = M + (i << 6);   // wave-uniform address -> s_load
            const float xv = xi[ii];
            #pragma unroll
            for (int k = 0; k < DIM; ++k)
                acc[k] = fmaf(xv, Mr[k], acc[k]);
        }
    }

    __syncthreads();   // done reading x tile; reuse LDS for output staging

    // ---- phase 3: stage output row into LDS (swizzled), then coalesced store ----
    #pragma unroll
    for (int g = 0; g < 16; ++g) {
        float4 v = make_float4(acc[g * 4 + 0], acc[g * 4 + 1],
                               acc[g * 4 + 2], acc[g * 4 + 3]);
        lds[(tid << 4) | (g ^ (tid & 15))] = v;
    }
    __syncthreads();

    float4* __restrict__ oo = (float4*)(out + base * DIM);
    #pragma unroll
    for (int it = 0; it < 16; ++it) {
        int idx = it * TILE_ROWS + tid;
        int r = idx >> 4;
        int c = idx & 15;
        oo[idx] = lds[(r << 4) | (c ^ (r & 15))];
    }
}

extern "C" void kernel_launch(void* const* d_in, const int* in_sizes, int n_in,
                              void* d_out, int out_size, void* d_ws, size_t ws_size,
                              hipStream_t stream) {
    const float* x = (const float*)d_in[0];
    const float* w = (const float*)d_in[1];
    float* out = (float*)d_out;
    float* M = (float*)d_ws;                 // 64*64*4 = 16 KB scratch

    int nrows = in_sizes[0] / DIM;           // 1048576

    build_M_kernel<<<16, 256, 0, stream>>>(w, M);

    int nblocks = (nrows + TILE_ROWS - 1) / TILE_ROWS;   // 4096
    gp_main_kernel<<<nblocks, TILE_ROWS, 0, stream>>>(x, M, out, nrows);
}